// Round 5
// baseline (197.360 us; speedup 1.0000x reference)
//
#include <hip/hip_runtime.h>
#include <hip/hip_bf16.h>
#include <cmath>

#define T_DIM 1024
#define B_DIM 8
#define C_DIM 256
#define H_DIM 8
#define D_DIM 32
#define F_DIM 512

typedef __attribute__((ext_vector_type(4))) float f32x4;
typedef __attribute__((ext_vector_type(8))) short bf16x8;

static __device__ __forceinline__ unsigned short f2bf(float f) {
    union { float f; unsigned u; } v; v.f = f;
    unsigned r = v.u + 0x7fff + ((v.u >> 16) & 1);
    return (unsigned short)(r >> 16);
}
static __device__ __forceinline__ float bf2f(unsigned short h) {
    union { unsigned u; float f; } v; v.u = ((unsigned)h) << 16;
    return v.f;
}

// async global->LDS, 16B per lane; LDS dest = wave-uniform base + lane*16
static __device__ __forceinline__ void gload_lds16(const void* g, void* l) {
    __builtin_amdgcn_global_load_lds(
        (const __attribute__((address_space(1))) unsigned int*)g,
        (__attribute__((address_space(3))) unsigned int*)l,
        16, 0, 0);
}

// ---------------------------------------------------------------------------
// Convert the 4 weight matrices f32 -> bf16 into one contiguous ws region.
// ---------------------------------------------------------------------------
__global__ __launch_bounds__(256) void convert_weights(const float* __restrict__ wqkv,
                                                       const float* __restrict__ wo,
                                                       const float* __restrict__ w1,
                                                       const float* __restrict__ w2,
                                                       unsigned short* __restrict__ dst)
{
    int e = blockIdx.x * 256 + threadIdx.x;
    const float* src; int off;
    if (e < 196608)      { src = wqkv; off = 0; }
    else if (e < 262144) { src = wo;   off = 196608; }
    else if (e < 393216) { src = w1;   off = 262144; }
    else                 { src = w2;   off = 393216; }
    dst[e] = f2bf(src[e - off]);
}

// ---------------------------------------------------------------------------
// LayerNorm, f32 input: one wave per row of C=256, float4 per lane, bf16 out.
// ---------------------------------------------------------------------------
__global__ __launch_bounds__(256) void ln_bf16(const float* __restrict__ x,
                                               const float* __restrict__ g,
                                               const float* __restrict__ bta,
                                               unsigned short* __restrict__ y)
{
    int row  = blockIdx.x * 4 + (threadIdx.x >> 6);
    int lane = threadIdx.x & 63;
    float4 v = ((const float4*)(x + (size_t)row * C_DIM))[lane];
    float s  = v.x + v.y + v.z + v.w;
    float ss = v.x * v.x + v.y * v.y + v.z * v.z + v.w * v.w;
#pragma unroll
    for (int off = 1; off < 64; off <<= 1) {
        s  += __shfl_xor(s, off);
        ss += __shfl_xor(ss, off);
    }
    float mu   = s * (1.0f / C_DIM);
    float var  = ss * (1.0f / C_DIM) - mu * mu;
    float rstd = rsqrtf(var + 1e-5f);
    float4 gv = ((const float4*)g)[lane];
    float4 bv = ((const float4*)bta)[lane];
    ushort4 o;
    o.x = f2bf((v.x - mu) * rstd * gv.x + bv.x);
    o.y = f2bf((v.y - mu) * rstd * gv.y + bv.y);
    o.z = f2bf((v.z - mu) * rstd * gv.z + bv.z);
    o.w = f2bf((v.w - mu) * rstd * gv.w + bv.w);
    ((ushort4*)(y + (size_t)row * C_DIM))[lane] = o;
}

// LayerNorm, bf16 input variant.
__global__ __launch_bounds__(256) void ln_bf16i(const unsigned short* __restrict__ x,
                                                const float* __restrict__ g,
                                                const float* __restrict__ bta,
                                                unsigned short* __restrict__ y)
{
    int row  = blockIdx.x * 4 + (threadIdx.x >> 6);
    int lane = threadIdx.x & 63;
    ushort4 hv = ((const ushort4*)(x + (size_t)row * C_DIM))[lane];
    float4 v = {bf2f(hv.x), bf2f(hv.y), bf2f(hv.z), bf2f(hv.w)};
    float s  = v.x + v.y + v.z + v.w;
    float ss = v.x * v.x + v.y * v.y + v.z * v.z + v.w * v.w;
#pragma unroll
    for (int off = 1; off < 64; off <<= 1) {
        s  += __shfl_xor(s, off);
        ss += __shfl_xor(ss, off);
    }
    float mu   = s * (1.0f / C_DIM);
    float var  = ss * (1.0f / C_DIM) - mu * mu;
    float rstd = rsqrtf(var + 1e-5f);
    float4 gv = ((const float4*)g)[lane];
    float4 bv = ((const float4*)bta)[lane];
    ushort4 o;
    o.x = f2bf((v.x - mu) * rstd * gv.x + bv.x);
    o.y = f2bf((v.y - mu) * rstd * gv.y + bv.y);
    o.z = f2bf((v.z - mu) * rstd * gv.z + bv.z);
    o.w = f2bf((v.w - mu) * rstd * gv.w + bv.w);
    ((ushort4*)(y + (size_t)row * C_DIM))[lane] = o;
}

// ---------------------------------------------------------------------------
// bf16 MFMA GEMM: out[m,n] = A[m,k] * W[n,k] + bias[n]
// BM=128, BN=64, BK=64, 4 waves. global_load_lds(16B), source-swizzled LDS.
// EPI: 0 store bf16 | 1 GELU->bf16 | 2 +R(f32)->bf16 | 3 +R(bf16)->f32
//      4 scatter QKV: Q_h/K_h [bh][t][d], V_t [bh][d][t]  (M index = t*8+b)
// ---------------------------------------------------------------------------
template<int EPI>
__global__ __launch_bounds__(256) void gemm_mfma(const unsigned short* __restrict__ A,
                                                 const unsigned short* __restrict__ W,
                                                 const float* __restrict__ bias,
                                                 const void* __restrict__ Rv,
                                                 void* __restrict__ outv,
                                                 int N, int K)
{
    __shared__ __align__(16) unsigned short A_s[128 * 64];
    __shared__ __align__(16) unsigned short W_s[64 * 64];
    int tid  = threadIdx.x;
    int lane = tid & 63;
    int wv   = tid >> 6;
    int l15  = lane & 15, lg = lane >> 4;
    int row0 = blockIdx.y * 128;
    int col0 = blockIdx.x * 64;

    f32x4 acc[2][4] = {};
    for (int k0 = 0; k0 < K; k0 += 64) {
#pragma unroll
        for (int i = 0; i < 4; i++) {                 // A tile: 128x64 bf16
            int u = (wv * 4 + i) * 64 + lane;
            int r = u >> 3, c = u & 7;
            gload_lds16(A + (size_t)(row0 + r) * K + k0 + ((c ^ (r & 7)) * 8),
                        &A_s[(size_t)(wv * 4 + i) * 512]);
        }
#pragma unroll
        for (int j = 0; j < 2; j++) {                 // W tile: 64x64 bf16
            int u = (wv * 2 + j) * 64 + lane;
            int r = u >> 3, c = u & 7;
            gload_lds16(W + (size_t)(col0 + r) * K + k0 + ((c ^ (r & 7)) * 8),
                        &W_s[(size_t)(wv * 2 + j) * 512]);
        }
        __syncthreads();
#pragma unroll
        for (int kk = 0; kk < 2; kk++) {
            bf16x8 af[2], wf[4];
#pragma unroll
            for (int mb = 0; mb < 2; mb++) {
                int rowa = wv * 32 + mb * 16 + l15;
                af[mb] = *(const bf16x8*)&A_s[rowa * 64 + (((kk * 4 + lg) ^ (l15 & 7)) * 8)];
            }
#pragma unroll
            for (int nb = 0; nb < 4; nb++) {
                int roww = nb * 16 + l15;
                wf[nb] = *(const bf16x8*)&W_s[roww * 64 + (((kk * 4 + lg) ^ (l15 & 7)) * 8)];
            }
#pragma unroll
            for (int mb = 0; mb < 2; mb++)
#pragma unroll
                for (int nb = 0; nb < 4; nb++)
                    acc[mb][nb] = __builtin_amdgcn_mfma_f32_16x16x32_bf16(af[mb], wf[nb], acc[mb][nb], 0, 0, 0);
        }
        __syncthreads();
    }
#pragma unroll
    for (int nb = 0; nb < 4; nb++) {
        int c = col0 + nb * 16 + l15;
        float bv = bias[c];
#pragma unroll
        for (int mb = 0; mb < 2; mb++) {
#pragma unroll
            for (int r = 0; r < 4; r++) {
                int rowm = row0 + wv * 32 + mb * 16 + lg * 4 + r;
                float v = acc[mb][nb][r] + bv;
                if (EPI == 4) {
                    // scatter to Q_h / K_h / V_t
                    unsigned short* qh = (unsigned short*)outv;
                    unsigned short* kh = qh + 2097152;
                    unsigned short* vt = qh + 4194304;
                    int t  = rowm >> 3, b_ = rowm & 7;
                    int h  = (c >> 5) & 7, d = c & 31;
                    int bh = b_ * 8 + h;
                    if (c < 256)      qh[(size_t)bh * 32768 + t * 32 + d] = f2bf(v);
                    else if (c < 512) kh[(size_t)bh * 32768 + t * 32 + d] = f2bf(v);
                    else              vt[(size_t)bh * 32768 + d * 1024 + t] = f2bf(v);
                } else if (EPI == 3) {
                    v += bf2f(((const unsigned short*)Rv)[(size_t)rowm * N + c]);
                    ((float*)outv)[(size_t)rowm * N + c] = v;
                } else {
                    if (EPI == 1) v = 0.5f * v * (1.0f + erff(v * 0.70710678118654752f));
                    if (EPI == 2) v += ((const float*)Rv)[(size_t)rowm * N + c];
                    ((unsigned short*)outv)[(size_t)rowm * N + c] = f2bf(v);
                }
            }
        }
    }
}

// ---------------------------------------------------------------------------
// Barrier-free flash attention, contiguous-layout operands, bias prefetch.
// Grid 1024 blocks x 256 thr = 4 independent waves; wave = (bh, 16 q-rows).
// Block mapping keeps all q-tiles of one bh on one XCD (bid%8 = bh%8).
// Q_h/K_h [bh][t][32], V_t [bh][32][t]: all fragment loads 16B contiguous.
// Bias prefetched 2 tiles deep into registers (HBM stream). P strip in LDS,
// XOR-swizzled (col ^= (l15&7)<<3): conflict-free b64 write / b128 read.
// ---------------------------------------------------------------------------
__global__ __launch_bounds__(256, 4) void attn_mfma(const unsigned short* __restrict__ Qh,
                                                    const unsigned short* __restrict__ Kh,
                                                    const unsigned short* __restrict__ Vt,
                                                    const float* __restrict__ bias,
                                                    const unsigned char* __restrict__ mask,
                                                    unsigned short* __restrict__ o)
{
    __shared__ unsigned short P_s[4][16][64];

    int tid  = threadIdx.x;
    int lane = tid & 63;
    int wv   = tid >> 6;
    int l15  = lane & 15, lg = lane >> 4;
    int bid  = blockIdx.x;
    int bh   = (bid & 7) + (bid >> 7) * 8;   // all 16 q-tiles of bh on one XCD
    int qg   = (bid >> 3) & 15;
    int b    = bh >> 3, hh = bh & 7;
    int q0   = qg * 64 + wv * 16;
    const float scale = 0.17677669529663687f;  // 1/sqrt(32)

    const unsigned short* kbase = Kh + (size_t)bh * 32768;
    const unsigned short* vbase = Vt + (size_t)bh * 32768;

    // Q fragment (B-operand): q = l15, d = lg*8..+7
    bf16x8 qf = *(const bf16x8*)(Qh + (size_t)bh * 32768 + (q0 + l15) * 32 + lg * 8);
    const float* bptr = bias + ((size_t)bh * T_DIM + q0 + l15) * T_DIM + lg * 4;
    const unsigned char* mptr = mask + (size_t)b * T_DIM + lg * 4;
    int swz = (l15 & 7) << 3;

    float m_run = -INFINITY, l_run = 0.0f;
    f32x4 oacc[2] = {};  // lane: q = l15, d = db*16 + lg*4 + r

    // 2-deep bias prefetch
    f32x4 bb[2][4];
#pragma unroll
    for (int kb = 0; kb < 4; kb++) {
        bb[0][kb] = *(const f32x4*)(bptr + kb * 16);
        bb[1][kb] = *(const f32x4*)(bptr + 64 + kb * 16);
    }

    for (int t = 0; t < 16; t++) {
        int k0 = t << 6;
        int cur = t & 1;

        // K fragments + mask (L2, contiguous 4KB per wave)
        bf16x8 kf[4];
        uint32_t mw[4];
#pragma unroll
        for (int kb = 0; kb < 4; kb++) {
            kf[kb] = *(const bf16x8*)(kbase + (size_t)(k0 + kb * 16 + l15) * 32 + lg * 8);
            mw[kb] = *(const uint32_t*)(mptr + k0 + kb * 16);
        }

        // ---- S^T = K @ Q^T (+scale +bias +mask) ----
        float sv[4][4];
        float tmax = -INFINITY;
        __builtin_amdgcn_s_setprio(1);
#pragma unroll
        for (int kb = 0; kb < 4; kb++) {
            f32x4 z = {0.0f, 0.0f, 0.0f, 0.0f};
            f32x4 sc = __builtin_amdgcn_mfma_f32_16x16x32_bf16(kf[kb], qf, z, 0, 0, 0);
#pragma unroll
            for (int r = 0; r < 4; r++) {
                float s = sc[r] * scale + bb[cur][kb][r];
                if ((mw[kb] >> (8 * r)) & 0xff) s = -1e9f;
                sv[kb][r] = s;
                tmax = fmaxf(tmax, s);
            }
        }
        __builtin_amdgcn_s_setprio(0);

        // V fragments for this tile (L2, contiguous; overlap softmax)
        bf16x8 vf[2][2];
#pragma unroll
        for (int h = 0; h < 2; h++)
#pragma unroll
            for (int db = 0; db < 2; db++)
                vf[h][db] = *(const bf16x8*)(vbase + (size_t)(db * 16 + l15) * 1024
                                             + k0 + h * 32 + lg * 8);

        // prefetch bias tile t+2 (overwrites consumed bb[cur])
        if (t < 14) {
#pragma unroll
            for (int kb = 0; kb < 4; kb++)
                bb[cur][kb] = *(const f32x4*)(bptr + ((t + 2) << 6) + kb * 16);
        }

        // ---- online softmax ----
        tmax = fmaxf(tmax, __shfl_xor(tmax, 16));
        tmax = fmaxf(tmax, __shfl_xor(tmax, 32));
        float m_new = fmaxf(m_run, tmax);
        float corr = __expf(m_run - m_new);
        m_run = m_new;

        float ls = 0.0f;
#pragma unroll
        for (int kb = 0; kb < 4; kb++) {
            float p0 = __expf(sv[kb][0] - m_new);
            float p1 = __expf(sv[kb][1] - m_new);
            float p2 = __expf(sv[kb][2] - m_new);
            float p3 = __expf(sv[kb][3] - m_new);
            ls += (p0 + p1) + (p2 + p3);
            uint2 pw;
            pw.x = (uint32_t)f2bf(p0) | ((uint32_t)f2bf(p1) << 16);
            pw.y = (uint32_t)f2bf(p2) | ((uint32_t)f2bf(p3) << 16);
            *(uint2*)&P_s[wv][l15][(kb * 16 + lg * 4) ^ swz] = pw;  // same-wave produce
        }
        ls += __shfl_xor(ls, 16);
        ls += __shfl_xor(ls, 32);
        l_run = l_run * corr + ls;
#pragma unroll
        for (int db = 0; db < 2; db++)
#pragma unroll
            for (int r = 0; r < 4; r++) oacc[db][r] *= corr;

        // ---- O^T += V^T @ P^T ----
        __builtin_amdgcn_s_setprio(1);
#pragma unroll
        for (int h = 0; h < 2; h++) {
            bf16x8 pf = *(const bf16x8*)&P_s[wv][l15][(h * 32 + lg * 8) ^ swz];
#pragma unroll
            for (int db = 0; db < 2; db++)
                oacc[db] = __builtin_amdgcn_mfma_f32_16x16x32_bf16(vf[h][db], pf, oacc[db], 0, 0, 0);
        }
        __builtin_amdgcn_s_setprio(0);
    }

    // direct store: token = q0+l15, dims d = db*16 + lg*4 + r (4 contiguous)
    float inv = 1.0f / l_run;
#pragma unroll
    for (int db = 0; db < 2; db++) {
        ushort4 ov;
        ov.x = f2bf(oacc[db][0] * inv);
        ov.y = f2bf(oacc[db][1] * inv);
        ov.z = f2bf(oacc[db][2] * inv);
        ov.w = f2bf(oacc[db][3] * inv);
        *(ushort4*)(o + ((size_t)(q0 + l15) * B_DIM + b) * C_DIM + hh * 32 + db * 16 + lg * 4) = ov;
    }
}

// ---------------------------------------------------------------------------
extern "C" void kernel_launch(void* const* d_in, const int* in_sizes, int n_in,
                              void* d_out, int out_size, void* d_ws, size_t ws_size,
                              hipStream_t stream)
{
    const float* x            = (const float*)d_in[0];
    const unsigned char* mask = (const unsigned char*)d_in[1];
    const float* bias         = (const float*)d_in[2];
    const float* ln1g         = (const float*)d_in[3];
    const float* ln1b         = (const float*)d_in[4];
    const float* ln2g         = (const float*)d_in[5];
    const float* ln2b         = (const float*)d_in[6];
    const float* wqkv         = (const float*)d_in[7];
    const float* bqkv         = (const float*)d_in[8];
    const float* wo           = (const float*)d_in[9];
    const float* bo           = (const float*)d_in[10];
    const float* w1           = (const float*)d_in[11];
    const float* b1           = (const float*)d_in[12];
    const float* w2           = (const float*)d_in[13];
    const float* b2           = (const float*)d_in[14];
    float* out = (float*)d_out;
    char* ws   = (char*)d_ws;

    unsigned short* wbf     = (unsigned short*)ws;                      // 1 MB
    unsigned short* wqkv_bf = wbf;
    unsigned short* wo_bf   = wbf + 196608;
    unsigned short* w1_bf   = wbf + 262144;
    unsigned short* w2_bf   = wbf + 393216;
    unsigned short* y_bf    = (unsigned short*)(ws + (1u << 20));       // 4 MB
    unsigned short* qkvs    = (unsigned short*)(ws + 5u * (1u << 20));  // 12 MB: Qh|Kh|Vt
    unsigned short* o_bf    = (unsigned short*)(ws + 17u * (1u << 20)); // 4 MB
    unsigned short* x1_bf   = (unsigned short*)(ws + 21u * (1u << 20)); // 4 MB
    unsigned short* h_bf    = (unsigned short*)(ws + 29u * (1u << 20)); // 8 MB

    unsigned short* Qh = qkvs;
    unsigned short* Kh = qkvs + 2097152;
    unsigned short* Vt = qkvs + 4194304;

    const int M = T_DIM * B_DIM;  // 8192

    convert_weights<<<2048, 256, 0, stream>>>(wqkv, wo, w1, w2, wbf);
    ln_bf16<<<M / 4, 256, 0, stream>>>(x, ln1g, ln1b, y_bf);
    gemm_mfma<4><<<dim3(768 / 64, M / 128), 256, 0, stream>>>(y_bf, wqkv_bf, bqkv, nullptr, qkvs, 768, 256);
    attn_mfma<<<1024, 256, 0, stream>>>(Qh, Kh, Vt, bias, mask, o_bf);
    gemm_mfma<2><<<dim3(256 / 64, M / 128), 256, 0, stream>>>(o_bf, wo_bf, bo, x, x1_bf, 256, 256);
    ln_bf16i<<<M / 4, 256, 0, stream>>>(x1_bf, ln2g, ln2b, y_bf);
    gemm_mfma<1><<<dim3(512 / 64, M / 128), 256, 0, stream>>>(y_bf, w1_bf, b1, nullptr, h_bf, 512, 256);
    gemm_mfma<3><<<dim3(256 / 64, M / 128), 256, 0, stream>>>(h_bf, w2_bf, b2, x1_bf, out, 256, 512);
}

// Round 6
// 138.964 us; speedup vs baseline: 1.4202x; 1.4202x over previous
//
#include <hip/hip_runtime.h>
#include <hip/hip_bf16.h>
#include <cmath>

#define T_DIM 1024
#define B_DIM 8
#define C_DIM 256
#define H_DIM 8
#define D_DIM 32
#define F_DIM 512

typedef __attribute__((ext_vector_type(4))) float f32x4;
typedef __attribute__((ext_vector_type(8))) short bf16x8;

static __device__ __forceinline__ unsigned short f2bf(float f) {
    union { float f; unsigned u; } v; v.f = f;
    unsigned r = v.u + 0x7fff + ((v.u >> 16) & 1);
    return (unsigned short)(r >> 16);
}
static __device__ __forceinline__ float bf2f(unsigned short h) {
    union { unsigned u; float f; } v; v.u = ((unsigned)h) << 16;
    return v.f;
}

// async global->LDS, 16B per lane; LDS dest = wave-uniform base + lane*16
static __device__ __forceinline__ void gload_lds16(const void* g, void* l) {
    __builtin_amdgcn_global_load_lds(
        (const __attribute__((address_space(1))) unsigned int*)g,
        (__attribute__((address_space(3))) unsigned int*)l,
        16, 0, 0);
}

// ---------------------------------------------------------------------------
// Convert the 4 weight matrices f32 -> bf16 into one contiguous ws region.
// ---------------------------------------------------------------------------
__global__ __launch_bounds__(256) void convert_weights(const float* __restrict__ wqkv,
                                                       const float* __restrict__ wo,
                                                       const float* __restrict__ w1,
                                                       const float* __restrict__ w2,
                                                       unsigned short* __restrict__ dst)
{
    int e = blockIdx.x * 256 + threadIdx.x;
    const float* src; int off;
    if (e < 196608)      { src = wqkv; off = 0; }
    else if (e < 262144) { src = wo;   off = 196608; }
    else if (e < 393216) { src = w1;   off = 262144; }
    else                 { src = w2;   off = 393216; }
    dst[e] = f2bf(src[e - off]);
}

// ---------------------------------------------------------------------------
// LayerNorm, f32 input: one wave per row of C=256, float4 per lane, bf16 out.
// ---------------------------------------------------------------------------
__global__ __launch_bounds__(256) void ln_bf16(const float* __restrict__ x,
                                               const float* __restrict__ g,
                                               const float* __restrict__ bta,
                                               unsigned short* __restrict__ y)
{
    int row  = blockIdx.x * 4 + (threadIdx.x >> 6);
    int lane = threadIdx.x & 63;
    float4 v = ((const float4*)(x + (size_t)row * C_DIM))[lane];
    float s  = v.x + v.y + v.z + v.w;
    float ss = v.x * v.x + v.y * v.y + v.z * v.z + v.w * v.w;
#pragma unroll
    for (int off = 1; off < 64; off <<= 1) {
        s  += __shfl_xor(s, off);
        ss += __shfl_xor(ss, off);
    }
    float mu   = s * (1.0f / C_DIM);
    float var  = ss * (1.0f / C_DIM) - mu * mu;
    float rstd = rsqrtf(var + 1e-5f);
    float4 gv = ((const float4*)g)[lane];
    float4 bv = ((const float4*)bta)[lane];
    ushort4 o;
    o.x = f2bf((v.x - mu) * rstd * gv.x + bv.x);
    o.y = f2bf((v.y - mu) * rstd * gv.y + bv.y);
    o.z = f2bf((v.z - mu) * rstd * gv.z + bv.z);
    o.w = f2bf((v.w - mu) * rstd * gv.w + bv.w);
    ((ushort4*)(y + (size_t)row * C_DIM))[lane] = o;
}

// LayerNorm, bf16 input variant.
__global__ __launch_bounds__(256) void ln_bf16i(const unsigned short* __restrict__ x,
                                                const float* __restrict__ g,
                                                const float* __restrict__ bta,
                                                unsigned short* __restrict__ y)
{
    int row  = blockIdx.x * 4 + (threadIdx.x >> 6);
    int lane = threadIdx.x & 63;
    ushort4 hv = ((const ushort4*)(x + (size_t)row * C_DIM))[lane];
    float4 v = {bf2f(hv.x), bf2f(hv.y), bf2f(hv.z), bf2f(hv.w)};
    float s  = v.x + v.y + v.z + v.w;
    float ss = v.x * v.x + v.y * v.y + v.z * v.z + v.w * v.w;
#pragma unroll
    for (int off = 1; off < 64; off <<= 1) {
        s  += __shfl_xor(s, off);
        ss += __shfl_xor(ss, off);
    }
    float mu   = s * (1.0f / C_DIM);
    float var  = ss * (1.0f / C_DIM) - mu * mu;
    float rstd = rsqrtf(var + 1e-5f);
    float4 gv = ((const float4*)g)[lane];
    float4 bv = ((const float4*)bta)[lane];
    ushort4 o;
    o.x = f2bf((v.x - mu) * rstd * gv.x + bv.x);
    o.y = f2bf((v.y - mu) * rstd * gv.y + bv.y);
    o.z = f2bf((v.z - mu) * rstd * gv.z + bv.z);
    o.w = f2bf((v.w - mu) * rstd * gv.w + bv.w);
    ((ushort4*)(y + (size_t)row * C_DIM))[lane] = o;
}

// ---------------------------------------------------------------------------
// bf16 MFMA GEMM: out[m,n] = A[m,k] * W[n,k] + bias[n]
// BM=128, BN=64, BK=64, 4 waves. global_load_lds(16B), source-swizzled LDS.
// EPI: 0 store bf16 | 1 GELU->bf16 | 2 +R(f32)->bf16 | 3 +R(bf16)->f32
//      4 scatter QKV: Q_h/K_h [bh][t][d], V_t [bh][d][t]  (M index = t*8+b)
// ---------------------------------------------------------------------------
template<int EPI>
__global__ __launch_bounds__(256) void gemm_mfma(const unsigned short* __restrict__ A,
                                                 const unsigned short* __restrict__ W,
                                                 const float* __restrict__ bias,
                                                 const void* __restrict__ Rv,
                                                 void* __restrict__ outv,
                                                 int N, int K)
{
    __shared__ __align__(16) unsigned short A_s[128 * 64];
    __shared__ __align__(16) unsigned short W_s[64 * 64];
    int tid  = threadIdx.x;
    int lane = tid & 63;
    int wv   = tid >> 6;
    int l15  = lane & 15, lg = lane >> 4;
    int row0 = blockIdx.y * 128;
    int col0 = blockIdx.x * 64;

    f32x4 acc[2][4] = {};
    for (int k0 = 0; k0 < K; k0 += 64) {
#pragma unroll
        for (int i = 0; i < 4; i++) {                 // A tile: 128x64 bf16
            int u = (wv * 4 + i) * 64 + lane;
            int r = u >> 3, c = u & 7;
            gload_lds16(A + (size_t)(row0 + r) * K + k0 + ((c ^ (r & 7)) * 8),
                        &A_s[(size_t)(wv * 4 + i) * 512]);
        }
#pragma unroll
        for (int j = 0; j < 2; j++) {                 // W tile: 64x64 bf16
            int u = (wv * 2 + j) * 64 + lane;
            int r = u >> 3, c = u & 7;
            gload_lds16(W + (size_t)(col0 + r) * K + k0 + ((c ^ (r & 7)) * 8),
                        &W_s[(size_t)(wv * 2 + j) * 512]);
        }
        __syncthreads();
#pragma unroll
        for (int kk = 0; kk < 2; kk++) {
            bf16x8 af[2], wf[4];
#pragma unroll
            for (int mb = 0; mb < 2; mb++) {
                int rowa = wv * 32 + mb * 16 + l15;
                af[mb] = *(const bf16x8*)&A_s[rowa * 64 + (((kk * 4 + lg) ^ (l15 & 7)) * 8)];
            }
#pragma unroll
            for (int nb = 0; nb < 4; nb++) {
                int roww = nb * 16 + l15;
                wf[nb] = *(const bf16x8*)&W_s[roww * 64 + (((kk * 4 + lg) ^ (l15 & 7)) * 8)];
            }
#pragma unroll
            for (int mb = 0; mb < 2; mb++)
#pragma unroll
                for (int nb = 0; nb < 4; nb++)
                    acc[mb][nb] = __builtin_amdgcn_mfma_f32_16x16x32_bf16(af[mb], wf[nb], acc[mb][nb], 0, 0, 0);
        }
        __syncthreads();
    }
#pragma unroll
    for (int nb = 0; nb < 4; nb++) {
        int c = col0 + nb * 16 + l15;
        float bv = bias[c];
#pragma unroll
        for (int mb = 0; mb < 2; mb++) {
#pragma unroll
            for (int r = 0; r < 4; r++) {
                int rowm = row0 + wv * 32 + mb * 16 + lg * 4 + r;
                float v = acc[mb][nb][r] + bv;
                if (EPI == 4) {
                    // scatter to Q_h / K_h / V_t
                    unsigned short* qh = (unsigned short*)outv;
                    unsigned short* kh = qh + 2097152;
                    unsigned short* vt = qh + 4194304;
                    int t  = rowm >> 3, b_ = rowm & 7;
                    int h  = (c >> 5) & 7, d = c & 31;
                    int bh = b_ * 8 + h;
                    if (c < 256)      qh[(size_t)bh * 32768 + t * 32 + d] = f2bf(v);
                    else if (c < 512) kh[(size_t)bh * 32768 + t * 32 + d] = f2bf(v);
                    else              vt[(size_t)bh * 32768 + d * 1024 + t] = f2bf(v);
                } else if (EPI == 3) {
                    v += bf2f(((const unsigned short*)Rv)[(size_t)rowm * N + c]);
                    ((float*)outv)[(size_t)rowm * N + c] = v;
                } else {
                    if (EPI == 1) v = 0.5f * v * (1.0f + erff(v * 0.70710678118654752f));
                    if (EPI == 2) v += ((const float*)Rv)[(size_t)rowm * N + c];
                    ((unsigned short*)outv)[(size_t)rowm * N + c] = f2bf(v);
                }
            }
        }
    }
}

// ---------------------------------------------------------------------------
// Flash attention, 2-phase pipelined bias stream (T3 minimum recipe).
// Grid 1024 x 256 thr = 4 waves; wave = (bh, 16 q-rows); bid%8 keeps a bh's
// q-tiles on one XCD. Per K-tile (64 keys):
//   issue gload_lds(bias tile t+1 -> buf^1)   [4 instrs/wave, in flight all
//   compute]  ->  S=K@Q^T + bias(LDS buf) -> softmax -> PV  ->  ONE barrier.
// Q_h/K_h [bh][t][32], V_t [bh][32][t]: K/V/Q frags are contiguous L2 loads.
// Bias LDS chunk per wave: f32 idx = p*256 + q*16 + (k&15), p=k>>4, staged by
// per-lane global source address (lane = q*4+j -> row q, cols j*4 + p*16).
// ---------------------------------------------------------------------------
__global__ __launch_bounds__(256, 4) void attn_mfma(const unsigned short* __restrict__ Qh,
                                                    const unsigned short* __restrict__ Kh,
                                                    const unsigned short* __restrict__ Vt,
                                                    const float* __restrict__ bias,
                                                    const unsigned char* __restrict__ mask,
                                                    unsigned short* __restrict__ o)
{
    __shared__ __align__(16) float bias_lds[2][4][1024];  // 32 KB: [buf][wave][chunk]
    __shared__ unsigned short P_s[4][16][64];             // 8 KB

    int tid  = threadIdx.x;
    int lane = tid & 63;
    int wv   = tid >> 6;
    int l15  = lane & 15, lg = lane >> 4;
    int bid  = blockIdx.x;
    int bh   = (bid & 7) + (bid >> 7) * 8;   // all 16 q-tiles of bh on one XCD
    int qg   = (bid >> 3) & 15;
    int b    = bh >> 3, hh = bh & 7;
    int q0   = qg * 64 + wv * 16;
    const float scale = 0.17677669529663687f;  // 1/sqrt(32)

    const unsigned short* kbase = Kh + (size_t)bh * 32768;
    const unsigned short* vbase = Vt + (size_t)bh * 32768;

    // Q fragment (B-operand): q = l15, d = lg*8..+7
    bf16x8 qf = *(const bf16x8*)(Qh + (size_t)bh * 32768 + (q0 + l15) * 32 + lg * 8);
    const unsigned char* mptr = mask + (size_t)b * T_DIM + lg * 4;
    int swz = (l15 & 7) << 3;

    // bias staging: lane = gq*4 + gj -> global row q0+gq, 16B chunk gj (+p*16)
    int gq = lane >> 2, gj = lane & 3;
    const float* bsrc = bias + ((size_t)bh * T_DIM + q0 + gq) * T_DIM + gj * 4;

    float m_run = -INFINITY, l_run = 0.0f;
    f32x4 oacc[2] = {};  // lane: q = l15, d = db*16 + lg*4 + r

    // prologue: stage bias tile 0 into buf 0
#pragma unroll
    for (int p = 0; p < 4; p++)
        gload_lds16(bsrc + p * 16, &bias_lds[0][wv][p * 256]);
    __syncthreads();

    for (int t = 0; t < 16; t++) {
        int k0  = t << 6;
        int buf = t & 1;

        // stage bias tile t+1 into buf^1 (in flight during this tile's compute)
        if (t < 15) {
#pragma unroll
            for (int p = 0; p < 4; p++)
                gload_lds16(bsrc + (t + 1) * 64 + p * 16, &bias_lds[buf ^ 1][wv][p * 256]);
        }

        // K fragments + mask (L2, contiguous)
        bf16x8 kf[4];
        uint32_t mw[4];
#pragma unroll
        for (int kb = 0; kb < 4; kb++) {
            kf[kb] = *(const bf16x8*)(kbase + (size_t)(k0 + kb * 16 + l15) * 32 + lg * 8);
            mw[kb] = *(const uint32_t*)(mptr + k0 + kb * 16);
        }

        // ---- S^T = K @ Q^T (+scale +bias +mask); bias from LDS buf ----
        float sv[4][4];
        float tmax = -INFINITY;
        __builtin_amdgcn_s_setprio(1);
#pragma unroll
        for (int kb = 0; kb < 4; kb++) {
            f32x4 z = {0.0f, 0.0f, 0.0f, 0.0f};
            f32x4 sc = __builtin_amdgcn_mfma_f32_16x16x32_bf16(kf[kb], qf, z, 0, 0, 0);
            f32x4 bv = *(const f32x4*)&bias_lds[buf][wv][kb * 256 + l15 * 16 + lg * 4];
#pragma unroll
            for (int r = 0; r < 4; r++) {
                float s = sc[r] * scale + bv[r];
                if ((mw[kb] >> (8 * r)) & 0xff) s = -1e9f;
                sv[kb][r] = s;
                tmax = fmaxf(tmax, s);
            }
        }
        __builtin_amdgcn_s_setprio(0);

        // V fragments (L2, contiguous; overlap softmax)
        bf16x8 vf[2][2];
#pragma unroll
        for (int h = 0; h < 2; h++)
#pragma unroll
            for (int db = 0; db < 2; db++)
                vf[h][db] = *(const bf16x8*)(vbase + (size_t)(db * 16 + l15) * 1024
                                             + k0 + h * 32 + lg * 8);

        // ---- online softmax ----
        tmax = fmaxf(tmax, __shfl_xor(tmax, 16));
        tmax = fmaxf(tmax, __shfl_xor(tmax, 32));
        float m_new = fmaxf(m_run, tmax);
        float corr = __expf(m_run - m_new);
        m_run = m_new;

        float ls = 0.0f;
#pragma unroll
        for (int kb = 0; kb < 4; kb++) {
            float p0 = __expf(sv[kb][0] - m_new);
            float p1 = __expf(sv[kb][1] - m_new);
            float p2 = __expf(sv[kb][2] - m_new);
            float p3 = __expf(sv[kb][3] - m_new);
            ls += (p0 + p1) + (p2 + p3);
            uint2 pw;
            pw.x = (uint32_t)f2bf(p0) | ((uint32_t)f2bf(p1) << 16);
            pw.y = (uint32_t)f2bf(p2) | ((uint32_t)f2bf(p3) << 16);
            *(uint2*)&P_s[wv][l15][(kb * 16 + lg * 4) ^ swz] = pw;  // same-wave produce
        }
        ls += __shfl_xor(ls, 16);
        ls += __shfl_xor(ls, 32);
        l_run = l_run * corr + ls;
#pragma unroll
        for (int db = 0; db < 2; db++)
#pragma unroll
            for (int r = 0; r < 4; r++) oacc[db][r] *= corr;

        // ---- O^T += V^T @ P^T ----
        __builtin_amdgcn_s_setprio(1);
#pragma unroll
        for (int h = 0; h < 2; h++) {
            bf16x8 pf = *(const bf16x8*)&P_s[wv][l15][(h * 32 + lg * 8) ^ swz];
#pragma unroll
            for (int db = 0; db < 2; db++)
                oacc[db] = __builtin_amdgcn_mfma_f32_16x16x32_bf16(vf[h][db], pf, oacc[db], 0, 0, 0);
        }
        __builtin_amdgcn_s_setprio(0);

        // ONE barrier per tile: drains gload(t+1), fences buf reuse
        __syncthreads();
    }

    // direct store: token = q0+l15, dims d = db*16 + lg*4 + r (4 contiguous)
    float inv = 1.0f / l_run;
#pragma unroll
    for (int db = 0; db < 2; db++) {
        ushort4 ov;
        ov.x = f2bf(oacc[db][0] * inv);
        ov.y = f2bf(oacc[db][1] * inv);
        ov.z = f2bf(oacc[db][2] * inv);
        ov.w = f2bf(oacc[db][3] * inv);
        *(ushort4*)(o + ((size_t)(q0 + l15) * B_DIM + b) * C_DIM + hh * 32 + db * 16 + lg * 4) = ov;
    }
}

// ---------------------------------------------------------------------------
extern "C" void kernel_launch(void* const* d_in, const int* in_sizes, int n_in,
                              void* d_out, int out_size, void* d_ws, size_t ws_size,
                              hipStream_t stream)
{
    const float* x            = (const float*)d_in[0];
    const unsigned char* mask = (const unsigned char*)d_in[1];
    const float* bias         = (const float*)d_in[2];
    const float* ln1g         = (const float*)d_in[3];
    const float* ln1b         = (const float*)d_in[4];
    const float* ln2g         = (const float*)d_in[5];
    const float* ln2b         = (const float*)d_in[6];
    const float* wqkv         = (const float*)d_in[7];
    const float* bqkv         = (const float*)d_in[8];
    const float* wo           = (const float*)d_in[9];
    const float* bo           = (const float*)d_in[10];
    const float* w1           = (const float*)d_in[11];
    const float* b1           = (const float*)d_in[12];
    const float* w2           = (const float*)d_in[13];
    const float* b2           = (const float*)d_in[14];
    float* out = (float*)d_out;
    char* ws   = (char*)d_ws;

    unsigned short* wbf     = (unsigned short*)ws;                      // 1 MB
    unsigned short* wqkv_bf = wbf;
    unsigned short* wo_bf   = wbf + 196608;
    unsigned short* w1_bf   = wbf + 262144;
    unsigned short* w2_bf   = wbf + 393216;
    unsigned short* y_bf    = (unsigned short*)(ws + (1u << 20));       // 4 MB
    unsigned short* qkvs    = (unsigned short*)(ws + 5u * (1u << 20));  // 12 MB: Qh|Kh|Vt
    unsigned short* o_bf    = (unsigned short*)(ws + 17u * (1u << 20)); // 4 MB
    unsigned short* x1_bf   = (unsigned short*)(ws + 21u * (1u << 20)); // 4 MB
    unsigned short* h_bf    = (unsigned short*)(ws + 29u * (1u << 20)); // 8 MB

    unsigned short* Qh = qkvs;
    unsigned short* Kh = qkvs + 2097152;
    unsigned short* Vt = qkvs + 4194304;

    const int M = T_DIM * B_DIM;  // 8192

    convert_weights<<<2048, 256, 0, stream>>>(wqkv, wo, w1, w2, wbf);
    ln_bf16<<<M / 4, 256, 0, stream>>>(x, ln1g, ln1b, y_bf);
    gemm_mfma<4><<<dim3(768 / 64, M / 128), 256, 0, stream>>>(y_bf, wqkv_bf, bqkv, nullptr, qkvs, 768, 256);
    attn_mfma<<<1024, 256, 0, stream>>>(Qh, Kh, Vt, bias, mask, o_bf);
    gemm_mfma<2><<<dim3(256 / 64, M / 128), 256, 0, stream>>>(o_bf, wo_bf, bo, x, x1_bf, 256, 256);
    ln_bf16i<<<M / 4, 256, 0, stream>>>(x1_bf, ln2g, ln2b, y_bf);
    gemm_mfma<1><<<dim3(512 / 64, M / 128), 256, 0, stream>>>(y_bf, w1_bf, b1, nullptr, h_bf, 512, 256);
    gemm_mfma<3><<<dim3(256 / 64, M / 128), 256, 0, stream>>>(h_bf, w2_bf, b2, x1_bf, out, 256, 512);
}